// Round 10
// baseline (363.242 us; speedup 1.0000x reference)
//
#include <hip/hip_runtime.h>

#define T_SEQ   2048
#define NHEADS  16
#define DHEAD   64
#define DMODEL  1024
#define ALPHA_C 1.4142135f
#define EPS_C   1e-5f

typedef __attribute__((ext_vector_type(8))) short bf16x8;
typedef __attribute__((ext_vector_type(4))) short bf16x4;
typedef __attribute__((ext_vector_type(4))) float floatx4;

__device__ __forceinline__ float bf2f(unsigned short u) {
  union { unsigned int i; float f; } v;
  v.i = ((unsigned int)u) << 16;
  return v.f;
}
__device__ __forceinline__ unsigned short f2bf(float f) {
  union { float f; unsigned int i; } v;
  v.f = f;
  unsigned int u = v.i;
  u += 0x7FFF + ((u >> 16) & 1);   // RNE (finite data only)
  return (unsigned short)(u >> 16);
}

__device__ __forceinline__ void gload_lds16(const void* g, void* l) {
  __builtin_amdgcn_global_load_lds(
      (const __attribute__((address_space(1))) void*)g,
      (__attribute__((address_space(3))) void*)l, 16, 0, 0);
}

// ---------------------------------------------------------------------------
// Merged f32->bf16 convert of all 5 inputs + RoPE LUT (one launch).
// ---------------------------------------------------------------------------
__global__ void convert_all(const float* __restrict__ Wqkv,
                            const float* __restrict__ Wout,
                            const float* __restrict__ W1,
                            const float* __restrict__ W2,
                            const float* __restrict__ x,
                            unsigned short* __restrict__ ws,
                            float* __restrict__ cosT,
                            float* __restrict__ sinT)
{
  if (blockIdx.x >= 10240) {                    // RoPE LUT tail blocks
    int gid = (blockIdx.x - 10240) * 256 + threadIdx.x;
    int t = gid >> 5, i = gid & 31;
    float fr = powf(10000.f, -(float)i * (1.f / 32.f));
    float sn, cs;
    sincosf((float)t * fr, &sn, &cs);
    cosT[gid] = cs;
    sinT[gid] = sn;
    return;
  }
  size_t i = ((size_t)blockIdx.x * 256 + threadIdx.x) * 8;
  const float* src;
  size_t off;
  if      (i <  3145728) { src = Wqkv; off = i; }
  else if (i <  4194304) { src = Wout; off = i -  3145728; }
  else if (i < 12582912) { src = W1;   off = i -  4194304; }
  else if (i < 16777216) { src = W2;   off = i - 12582912; }
  else                   { src = x;    off = i - 16777216; }
  floatx4 a = *(const floatx4*)(src + off);
  floatx4 b = *(const floatx4*)(src + off + 4);
  bf16x8 o;
  #pragma unroll
  for (int u = 0; u < 4; u++) {
    o[u]     = (short)f2bf(a[u]);
    o[4 + u] = (short)f2bf(b[u]);
  }
  *(bf16x8*)(ws + i) = o;
}

// ---------------------------------------------------------------------------
// 256-tile split-lgkm 4-phase template, depth-2 staging (unchanged).
// ---------------------------------------------------------------------------
#define BAR() __builtin_amdgcn_s_barrier()
#define SCB() __builtin_amdgcn_sched_barrier(0)

#define RD_A_S(bb, mh, s)                                                 \
  _Pragma("unroll") for (int i = 0; i < 4; i++)                           \
    af[i][s] = *(const bf16x8*)&lds[(bb) + aRd +                          \
        ((mh) * 64 + i * 16 + mrow) * 64 + (kq0 ^ ((s) << 5))];

#define RD_B_S(bb, s)                                                     \
  _Pragma("unroll") for (int n = 0; n < 4; n++)                           \
    bfr[n][s] = *(const bf16x8*)&lds[(bb) + bRd +                         \
        (bRow0 + n * 16 + mrow) * 64 + (kq0 ^ ((s) << 5))];

#define MFMA8(mh, nh, s)                                                  \
  _Pragma("unroll") for (int i = 0; i < 4; i++)                           \
  _Pragma("unroll") for (int n = 0; n < 2; n++)                           \
    acc[(mh) * 4 + i][(nh) * 2 + n] =                                     \
        __builtin_amdgcn_mfma_f32_16x16x32_bf16(                          \
            af[i][s], bfr[(nh) * 2 + n][s],                               \
            acc[(mh) * 4 + i][(nh) * 2 + n], 0, 0, 0);

#define KLOOP_S4()                                                        \
  for (int t = 0; t < 16; ++t) {                                          \
    const int cur = t & 1;                                                \
    const int bb  = cur * 32768;                                          \
    const int tb  = (t + 2 < 16) ? t + 2 : 15;                            \
    /* phase 1: reads a0 + all B (split 8/0), no stage */                 \
    BAR();                                                                \
    RD_A_S(bb, 0, 0); RD_B_S(bb, 0);                                      \
    SCB();                                                                \
    RD_A_S(bb, 0, 1); RD_B_S(bb, 1);                                      \
    asm volatile("s_waitcnt lgkmcnt(8)" ::: "memory");                    \
    SCB();                                                                \
    __builtin_amdgcn_s_setprio(1);                                        \
    MFMA8(0, 0, 0);                                                       \
    __builtin_amdgcn_s_setprio(0);                                        \
    asm volatile("s_waitcnt lgkmcnt(0)" ::: "memory");                    \
    SCB();                                                                \
    __builtin_amdgcn_s_setprio(1);                                        \
    MFMA8(0, 0, 1);                                                       \
    __builtin_amdgcn_s_setprio(0);                                        \
    /* phase 2: stage B[cur]<-t+2 (4 gl), pure MFMA */                    \
    BAR();                                                                \
    stB(cur, 0, tb); stB(cur, 1, tb);                                     \
    __builtin_amdgcn_s_setprio(1);                                        \
    MFMA8(0, 1, 0); MFMA8(0, 1, 1);                                       \
    __builtin_amdgcn_s_setprio(0);                                        \
    /* phase 3: reads a1 (split 4/0), no stage */                         \
    BAR();                                                                \
    RD_A_S(bb, 1, 0);                                                     \
    SCB();                                                                \
    RD_A_S(bb, 1, 1);                                                     \
    asm volatile("s_waitcnt lgkmcnt(4)" ::: "memory");                    \
    SCB();                                                                \
    __builtin_amdgcn_s_setprio(1);                                        \
    MFMA8(1, 1, 0);                                                       \
    __builtin_amdgcn_s_setprio(0);                                        \
    asm volatile("s_waitcnt lgkmcnt(0)" ::: "memory");                    \
    SCB();                                                                \
    __builtin_amdgcn_s_setprio(1);                                        \
    MFMA8(1, 1, 1);                                                       \
    __builtin_amdgcn_s_setprio(0);                                        \
    /* phase 4: stage A[cur]<-t+2 (4 gl), pure MFMA, vmcnt(8) */          \
    BAR();                                                                \
    stA(cur, 0, tb); stA(cur, 1, tb);                                     \
    __builtin_amdgcn_s_setprio(1);                                        \
    MFMA8(1, 0, 0); MFMA8(1, 0, 1);                                       \
    __builtin_amdgcn_s_setprio(0);                                        \
    asm volatile("s_waitcnt vmcnt(8)" ::: "memory");                      \
  }

// ---------------------------------------------------------------------------
// W1 GEMM + fused SwiGLU — depth-2 split-lgkm schedule (unchanged).
// ---------------------------------------------------------------------------
__global__ __launch_bounds__(512, 2) void gemm_w1_swiglu_s4(
    const unsigned short* __restrict__ A,    // x2 [4096][1024]
    const unsigned short* __restrict__ W1,   // [8192][1024]
    unsigned short* __restrict__ ys)         // [4096][4096]
{
  __shared__ unsigned short lds[65536];

  const int tid  = threadIdx.x;
  const int lane = tid & 63;
  const int wid  = tid >> 6;
  const int wr   = wid >> 2;     // M half
  const int wc   = wid & 3;      // N quarter
  const int mrow = lane & 15;
  const int quad = lane >> 4;
  const int kq0  = (quad ^ (mrow & 7)) * 8;   // full st-swizzle

  const int bid  = blockIdx.x;
  const int c8   = bid & 7;
  const int u    = bid >> 3;     // 0..63
  const int mBase = ((c8 >> 2) * 8 + (u >> 3)) * 256;
  const int nBase = ((c8 &  3) * 8 + (u &  7)) * 128;

  const int r0 = tid >> 3;
  const int ce = (((tid & 7) ^ (r0 & 7)) * 8);
  const size_t aoff0 = (size_t)(mBase + r0) * 1024 + ce;
  const size_t aoff1 = aoff0 + (size_t)64 * 1024;
  auto growf = [&](int br) {
    int col = nBase + (br >> 6) * 32 + (br & 31);
    return ((br >> 5) & 1) ? 4096 + col : col;
  };
  const size_t boff00 = (size_t)growf(r0)       * 1024 + ce;
  const size_t boff01 = (size_t)growf(64 + r0)  * 1024 + ce;
  const size_t boff10 = (size_t)growf(128 + r0) * 1024 + ce;
  const size_t boff11 = (size_t)growf(192 + r0) * 1024 + ce;
  const int d0 = tid * 8;

  auto stA = [&](int buf, int h, int kt) {
    const unsigned short* g = A + (size_t)kt * 64 + (h ? (size_t)128 * 1024 : 0);
    int base = buf * 32768 + h * 8192;
    gload_lds16(g + aoff0, &lds[base + d0]);
    gload_lds16(g + aoff1, &lds[base + 4096 + d0]);
  };
  auto stB = [&](int buf, int h, int kt) {
    const unsigned short* g = W1 + (size_t)kt * 64;
    int base = buf * 32768 + 16384 + h * 8192;
    gload_lds16(g + (h ? boff10 : boff00), &lds[base + d0]);
    gload_lds16(g + (h ? boff11 : boff01), &lds[base + 4096 + d0]);
  };

  floatx4 acc[8][4];
  #pragma unroll
  for (int i = 0; i < 8; i++)
    #pragma unroll
    for (int n = 0; n < 4; n++) acc[i][n] = (floatx4){0.f, 0.f, 0.f, 0.f};
  bf16x8 af[4][2], bfr[4][2];

  const int aRd   = wr * 8192;
  const int bRd   = 16384 + (wc >> 1) * 8192;
  const int bRow0 = (wc & 1) * 64;

  // prologue: full tile0 + full tile1 (16 gloads); vmcnt(8) drains tile0
  stB(0, 0, 0); stB(0, 1, 0); stA(0, 0, 0); stA(0, 1, 0);
  stB(1, 0, 1); stB(1, 1, 1); stA(1, 0, 1); stA(1, 1, 1);
  asm volatile("s_waitcnt vmcnt(8)" ::: "memory");

  KLOOP_S4();

  // epilogue: SwiGLU in-register (y = acc[][n], gate = acc[][n+2])
  const int col0 = lane & 15;
  const int row0 = (lane >> 4) * 4;
  #pragma unroll
  for (int n = 0; n < 2; n++) {
    const int col = nBase + wc * 32 + n * 16 + col0;
    #pragma unroll
    for (int i = 0; i < 8; i++) {
      const int rowb = mBase + wr * 128 + i * 16 + row0;
      #pragma unroll
      for (int r = 0; r < 4; r++) {
        float y = acc[i][n][r], g = acc[i][n + 2][r];
        float sig = 1.f / (1.f + __expf(-g));
        ys[(size_t)(rowb + r) * 4096 + col] = f2bf(y * g * sig);
      }
    }
  }
  asm volatile("s_waitcnt vmcnt(0)" ::: "memory");
}

// ---------------------------------------------------------------------------
// qkv GEMM + fused RoPE, depth-2 split-lgkm schedule (unchanged).
// ---------------------------------------------------------------------------
__global__ __launch_bounds__(512, 2) void gemm_qkv_rope256(
    const unsigned short* __restrict__ A,    // xb [4096][1024]
    const unsigned short* __restrict__ W,    // Wqkv [3072][1024]
    const float* __restrict__ cosT,
    const float* __restrict__ sinT,
    unsigned short* __restrict__ Qd,
    unsigned short* __restrict__ Kd,
    unsigned short* __restrict__ Vd)
{
  __shared__ unsigned short lds[65536];

  const int tid  = threadIdx.x;
  const int lane = tid & 63;
  const int wid  = tid >> 6;
  const int wr   = wid >> 2;     // M half
  const int wc   = wid & 3;      // N quarter (one 64-col head)
  const int mrow = lane & 15;
  const int quad = lane >> 4;
  const int kq0  = (quad ^ (mrow & 7)) * 8;

  // XCD map over 192 blocks: bijective.
  const int bid  = blockIdx.x;
  const int c8   = bid & 7;
  const int u    = bid >> 3;
  const int mBase = ((c8 >> 1) * 4 + u / 6) * 256;
  const int nBase = ((c8 & 1) * 6 + u % 6) * 256;

  const int r0 = tid >> 3;
  const int ce = (((tid & 7) ^ (r0 & 7)) * 8);
  const size_t aoff0 = (size_t)(mBase + r0) * 1024 + ce;
  const size_t aoff1 = aoff0 + (size_t)64 * 1024;
  const size_t boff00 = (size_t)(nBase + r0)       * 1024 + ce;
  const size_t boff01 = (size_t)(nBase + 64 + r0)  * 1024 + ce;
  const size_t boff10 = (size_t)(nBase + 128 + r0) * 1024 + ce;
  const size_t boff11 = (size_t)(nBase + 192 + r0) * 1024 + ce;
  const int d0 = tid * 8;

  auto stA = [&](int buf, int h, int kt) {
    const unsigned short* g = A + (size_t)kt * 64 + (h ? (size_t)128 * 1024 : 0);
    int base = buf * 32768 + h * 8192;
    gload_lds16(g + aoff0, &lds[base + d0]);
    gload_lds16(g + aoff1, &lds[base + 4096 + d0]);
  };
  auto stB = [&](int buf, int h, int kt) {
    const unsigned short* g = W + (size_t)kt * 64;
    int base = buf * 32768 + 16384 + h * 8192;
    gload_lds16(g + (h ? boff10 : boff00), &lds[base + d0]);
    gload_lds16(g + (h ? boff11 : boff01), &lds[base + 4096 + d0]);
  };

  floatx4 acc[8][4];
  #pragma unroll
  for (int i = 0; i < 8; i++)
    #pragma unroll
    for (int n = 0; n < 4; n++) acc[i][n] = (floatx4){0.f, 0.f, 0.f, 0.f};
  bf16x8 af[4][2], bfr[4][2];

  const int aRd   = wr * 8192;
  const int bRd   = 16384 + (wc >> 1) * 8192;
  const int bRow0 = (wc & 1) * 64;

  // prologue: full tile0 + full tile1; vmcnt(8) drains tile0
  stB(0, 0, 0); stB(0, 1, 0); stA(0, 0, 0); stA(0, 1, 0);
  stB(1, 0, 1); stB(1, 1, 1); stA(1, 0, 1); stA(1, 1, 1);
  asm volatile("s_waitcnt vmcnt(8)" ::: "memory");

  KLOOP_S4();

  // ---- epilogue: RoPE (q,k) / plain store (v) ----
  const int col0 = lane & 15;
  const int row0 = (lane >> 4) * 4;
  const int colBase = nBase + wc * 64;     // wave-uniform, one head
  const int sect = colBase >> 10;          // 0=q, 1=k, 2=v
  const int h    = (colBase & 1023) >> 6;  // head index
  unsigned short* dst = (sect == 0) ? Qd : (sect == 1) ? Kd : Vd;

  if (sect < 2) {
    #pragma unroll
    for (int i = 0; i < 8; i++) {
      #pragma unroll
      for (int r = 0; r < 4; r++) {
        const int row = mBase + wr * 128 + i * 16 + row0 + r;
        const int b = row >> 11, t = row & 2047;
        size_t ob = ((size_t)((b * NHEADS + h) * T_SEQ + t)) * DHEAD;
        const int tb = t * 32;
        float c0 = cosT[tb + col0],      s0 = sinT[tb + col0];
        float c1 = cosT[tb + col0 + 16], s1 = sinT[tb + col0 + 16];
        float x1a = acc[i][0][r], x2a = acc[i][2][r];
        float x1b = acc[i][1][r], x2b = acc[i][3][r];
        dst[ob + col0]      = f2bf(x1a * c0 - x2a * s0);
        dst[ob + col0 + 32] = f2bf(x2a * c0 + x1a * s0);
        dst[ob + col0 + 16] = f2bf(x1b * c1 - x2b * s1);
        dst[ob + col0 + 48] = f2bf(x2b * c1 + x1b * s1);
      }
    }
  } else {
    #pragma unroll
    for (int i = 0; i < 8; i++)
      #pragma unroll
      for (int n = 0; n < 4; n++)
        #pragma unroll
        for (int r = 0; r < 4; r++) {
          const int row = mBase + wr * 128 + i * 16 + row0 + r;
          const int b = row >> 11, t = row & 2047;
          dst[((size_t)((b * NHEADS + h) * T_SEQ + t)) * DHEAD + n * 16 + col0] =
              f2bf(acc[i][n][r]);
        }
  }
  asm volatile("s_waitcnt vmcnt(0)" ::: "memory");
}

// ---------------------------------------------------------------------------
// W2 GEMM, single-pass K=4096 -> y2 f32 (unchanged from round 9).
// ---------------------------------------------------------------------------
#define W1K_RD_A(bb, s)                                                   \
  _Pragma("unroll") for (int i = 0; i < 4; i++)                           \
    af[i][s] = *(const bf16x8*)&lds[(bb) +                                \
        (wr * 64 + i * 16 + mrow) * 64 + (kq0 ^ ((s) << 5))];

#define W1K_RD_B(bb, s)                                                   \
  _Pragma("unroll") for (int n = 0; n < 2; n++)                           \
    bfr[n][s] = *(const bf16x8*)&lds[(bb) + 16384 +                       \
        (wc * 32 + n * 16 + mrow) * 64 + (kq0 ^ ((s) << 5))];

#define W1K_MFMA(s)                                                       \
  _Pragma("unroll") for (int i = 0; i < 4; i++)                           \
  _Pragma("unroll") for (int n = 0; n < 2; n++)                           \
    acc[i][n] = __builtin_amdgcn_mfma_f32_16x16x32_bf16(                  \
        af[i][s], bfr[n][s], acc[i][n], 0, 0, 0);

__global__ __launch_bounds__(512, 2) void gemm_w2_1k(
    const unsigned short* __restrict__ A,    // ys [4096][4096]
    const unsigned short* __restrict__ W,    // W2 [1024][4096]
    float* __restrict__ y2)                  // [4096][1024] f32
{
  __shared__ unsigned short lds[40960];      // 2 x (A 16384 + B 4096)

  const int tid  = threadIdx.x;
  const int lane = tid & 63;
  const int wid  = tid >> 6;
  const int wr   = wid >> 1;     // M quarter (64 rows)
  const int wc   = wid & 1;      // N half (32 cols)
  const int mrow = lane & 15;
  const int quad = lane >> 4;
  const int kq0  = (quad ^ (mrow & 7)) * 8;

  const int u  = blockIdx.x;
  const int c8 = u & 7;
  const int v  = u >> 3;
  const int mBase = ((c8 >> 1) * 4 + (v >> 3)) * 256;
  const int nBase = ((c8 & 1) * 8 + (v & 7)) * 64;

  const int r0 = tid >> 3;
  const int ce = (((tid & 7) ^ (r0 & 7)) * 8);
  const int d0 = tid * 8;

  auto stA = [&](int buf, int h, int kt) {
    const unsigned short* g =
        A + (size_t)(mBase + h * 128 + r0) * 4096 + kt * 64 + ce;
    int base = buf * 20480 + h * 8192;
    gload_lds16(g, &lds[base + d0]);
    gload_lds16(g + (size_t)64 * 4096, &lds[base + 4096 + d0]);
  };
  auto stB = [&](int buf, int kt) {
    const unsigned short* g =
        W + (size_t)(nBase + r0) * 4096 + kt * 64 + ce;
    gload_lds16(g, &lds[buf * 20480 + 16384 + d0]);
  };

  floatx4 acc[4][2];
  #pragma unroll
  for (int i = 0; i < 4; i++)
    #pragma unroll
    for (int n = 0; n < 2; n++) acc[i][n] = (floatx4){0.f, 0.f, 0.f, 0.f};
  bf16x8 af[4][2], bfr[2][2];

  stB(0, 0);
  stA(0, 0, 0); stA(0, 1, 0);
  stB(1, 1);
  asm volatile("s_waitcnt vmcnt(1)" ::: "memory");

  for (int t = 0; t < 64; ++t) {
    const int cur = t & 1;
    const int nxt = cur ^ 1;
    const int bb  = cur * 20480;
    const int ta  = (t + 1 < 64) ? t + 1 : 63;
    const int tb  = (t + 2 < 64) ? t + 2 : 63;

    BAR();
    W1K_RD_A(bb, 0); W1K_RD_B(bb, 0);
    SCB();
    W1K_RD_A(bb, 1); W1K_RD_B(bb, 1);
    asm volatile("s_waitcnt lgkmcnt(6)" ::: "memory");
    SCB();
    __builtin_amdgcn_s_setprio(1);
    W1K_MFMA(0);
    __builtin_amdgcn_s_setprio(0);
    asm volatile("s_waitcnt lgkmcnt(0)" ::: "memory");
    SCB();
    stA(nxt, 0, ta); stA(nxt, 1, ta);
    stB(cur, tb);
    __builtin_amdgcn_s_setprio(1);
    W1K_MFMA(1);
    __builtin_amdgcn_s_setprio(0);
    asm volatile("s_waitcnt vmcnt(1)" ::: "memory");
  }

  const int col0 = lane & 15;
  const int row0 = (lane >> 4) * 4;
  #pragma unroll
  for (int n = 0; n < 2; n++) {
    const int col = nBase + wc * 32 + n * 16 + col0;
    #pragma unroll
    for (int i = 0; i < 4; i++) {
      const int rowb = mBase + wr * 64 + i * 16 + row0;
      #pragma unroll
      for (int r = 0; r < 4; r++)
        y2[(size_t)(rowb + r) * 1024 + col] = acc[i][n][r];
    }
  }
  asm volatile("s_waitcnt vmcnt(0)" ::: "memory");
}

// ---------------------------------------------------------------------------
// Shared 2-phase 256x128 template macros (wout).
// ---------------------------------------------------------------------------
#define W2_RD_A(bb, mh, s)                                                \
  _Pragma("unroll") for (int i = 0; i < 2; i++)                           \
    af[i][s] = *(const bf16x8*)&lds[(bb) +                                \
        (wr * 64 + (mh) * 32 + i * 16 + mrow) * 64 + (kq0 ^ ((s) << 5))];

#define W2_RD_B(bb, s)                                                    \
  _Pragma("unroll") for (int n = 0; n < 4; n++)                           \
    bfr[n][s] = *(const bf16x8*)&lds[(bb) + 16384 +                       \
        (wc * 64 + n * 16 + mrow) * 64 + (kq0 ^ ((s) << 5))];

#define W2_MFMA(mh, s)                                                    \
  _Pragma("unroll") for (int i = 0; i < 2; i++)                           \
  _Pragma("unroll") for (int n = 0; n < 4; n++)                           \
    acc[(mh) * 2 + i][n] =                                                \
        __builtin_amdgcn_mfma_f32_16x16x32_bf16(                          \
            af[i][s], bfr[n][s], acc[(mh) * 2 + i][n], 0, 0, 0);

#define W2_KLOOP(NT)                                                      \
  for (int t = 0; t < (NT); ++t) {                                        \
    const int cur = t & 1;                                                \
    const int nxt = cur ^ 1;                                              \
    const int bb  = cur * 24576;                                          \
    const int ta  = (t + 1 < (NT)) ? t + 1 : (NT) - 1;                    \
    const int tb  = (t + 2 < (NT)) ? t + 2 : (NT) - 1;                    \
    BAR();                                                                \
    stA(nxt, 0, ta); stA(nxt, 1, ta);                                     \
    W2_RD_A(bb, 0, 0); W2_RD_B(bb, 0);                                    \
    SCB();                                                                \
    W2_RD_A(bb, 0, 1); W2_RD_B(bb, 1);                                    \
    asm volatile("s_waitcnt lgkmcnt(6)" ::: "memory");                    \
    SCB();                                                                \
    __builtin_amdgcn_s_setprio(1);                                        \
    W2_MFMA(0, 0);                                                        \
    __builtin_amdgcn_s_setprio(0);                                        \
    asm volatile("s_waitcnt lgkmcnt(0)" ::: "memory");                    \
    SCB();                                                                \
    __builtin_amdgcn_s_setprio(1);                                        \
    W2_MFMA(0, 1);                                                        \
    __builtin_amdgcn_s_setprio(0);                                        \
    BAR();                                                                \
    stB(cur, tb);                                                         \
    W2_RD_A(bb, 1, 0);                                                    \
    SCB();                                                                \
    W2_RD_A(bb, 1, 1);                                                    \
    asm volatile("s_waitcnt lgkmcnt(2)" ::: "memory");                    \
    SCB();                                                                \
    __builtin_amdgcn_s_setprio(1);                                        \
    W2_MFMA(1, 0);                                                        \
    __builtin_amdgcn_s_setprio(0);                                        \
    asm volatile("s_waitcnt lgkmcnt(0)" ::: "memory");                    \
    SCB();                                                                \
    __builtin_amdgcn_s_setprio(1);                                        \
    W2_MFMA(1, 1);                                                        \
    __builtin_amdgcn_s_setprio(0);                                        \
    asm volatile("s_waitcnt vmcnt(2)" ::: "memory");                      \
  }

// ---------------------------------------------------------------------------
// Wout projection, 2-phase template (unchanged).
// ---------------------------------------------------------------------------
__global__ __launch_bounds__(512, 2) void gemm_wout_2ph(
    const unsigned short* __restrict__ A,    // o [4096][1024]
    const unsigned short* __restrict__ W,    // Wout [1024][1024]
    const float* __restrict__ bias,          // bout [1024]
    unsigned short* __restrict__ C)          // P1 [4096][1024]
{
  __shared__ unsigned short lds[49152];      // 2 x 24576 (A 16384 + B 8192)

  const int tid  = threadIdx.x;
  const int lane = tid & 63;
  const int wid  = tid >> 6;
  const int wr   = wid >> 1;     // M quarter
  const int wc   = wid & 1;      // N half
  const int mrow = lane & 15;
  const int quad = lane >> 4;
  const int kq0  = (quad ^ (mrow & 7)) * 8;

  const int u  = blockIdx.x;
  const int c8 = u & 7;
  const int v  = u >> 3;                     // 0..15
  const int mBase = ((c8 >> 1) * 4 + (v >> 2)) * 256;
  const int nBase = ((c8 & 1) * 4 + (v & 3)) * 128;

  const int r0 = tid >> 3;
  const int ce = (((tid & 7) ^ (r0 & 7)) * 8);
  const int d0 = tid * 8;

  auto stA = [&](int buf, int h, int kt) {
    const unsigned short* g =
        A + (size_t)(mBase + h * 128 + r0) * 1024 + kt * 64 + ce;
    int base = buf * 24576 + h * 8192;
    gload_lds16(g, &lds[base + d0]);
    gload_lds16(g + (size_t)64 * 1024, &lds[base + 4096 + d0]);
  };
  auto stB = [&](int buf, int kt) {
    const unsigned short* g =
        W + (size_t)(nBase + r0) * 1024 + kt * 64 + ce;
    int base = buf * 24576 + 16384;
    gload_lds16(g, &lds[base + d0]);
    gload_lds16(g + (size_t)64 * 1024, &lds[base + 4096 + d0]);
  };

  floatx4 acc[4][4];
  #pragma unroll
  for (int i = 0; i < 4; i++)
    #pragma unroll
    for (int n = 0; n < 4; n++) acc[i][n] = (floatx4){0.f, 0.f, 0.f, 0.f};
  bf16x8 af[2][2], bfr[4][2];

  stB(0, 0);
  stA(0, 0, 0); stA(0, 1, 0);
  stB(1, 1);
  asm volatile("s_waitcnt vmcnt(2)" ::: "memory");

  W2_KLOOP(16);

  const int col0 = lane & 15;
  const int row0 = (lane >> 4) * 4;
  #pragma unroll
  for (int n = 0; n < 4; n++) {
    const int col = nBase + wc * 64 + n * 16 + col0;
    const float badd = bias[col];
    #pragma unroll
    for (int i = 0; i < 4; i++) {
      const int rowb = mBase + wr * 64 + i * 16 + row0;
      #pragma unroll
      for (int r = 0; r < 4; r++)
        C[(size_t)(rowb + r) * 1024 + col] = f2bf(acc[i][n][r] + badd);
    }
  }
  asm volatile("s_waitcnt vmcnt(0)" ::: "memory");
}

// ---------------------------------------------------------------------------
// MFMA banded attention (unchanged).
// ---------------------------------------------------------------------------
__global__ __launch_bounds__(256) void attn_mfma(
    const unsigned short* __restrict__ Qg,
    const unsigned short* __restrict__ Kg,
    const unsigned short* __restrict__ Vg,
    unsigned short* __restrict__ Og)
{
  __shared__ unsigned short KV[23040];   // K tile [320][72]; then V^T [64][328]
  __shared__ unsigned short Qs[64 * 72];
  __shared__ unsigned short Ps[4 * 16 * 328];

  const int tid  = threadIdx.x;
  const int lane = tid & 63;
  const int wave = tid >> 6;
  const int c    = lane & 15;
  const int quad = lane >> 4;
  const int blk  = blockIdx.x;
  const int bh   = blk >> 5;
  const int qBase = (blk & 31) * 64;
  const size_t hbase = (size_t)bh * T_SEQ * DHEAD;

  for (int e = tid; e < 320 * 8; e += 256) {
    int row = e >> 3, ch = e & 7;
    int kg = qBase - 127 + row;
    int kgc = min(max(kg, 0), T_SEQ - 1);
    *(bf16x8*)&KV[row * 72 + ch * 8] =
        *(const bf16x8*)(Kg + hbase + (size_t)kgc * DHEAD + ch * 8);
  }
  for (int e = tid; e < 64 * 8; e += 256) {
    int row = e >> 3, ch = e & 7;
    *(bf16x8*)&Qs[row * 72 + ch * 8] =
        *(const bf16x8*)(Qg + hbase + (size_t)(qBase + row) * DHEAD + ch * 8);
  }
  __syncthreads();

  bf16x8 aq[2];
  #pragma unroll
  for (int hh = 0; hh < 2; hh++)
    aq[hh] = *(const bf16x8*)&Qs[(wave * 16 + c) * 72 + hh * 32 + quad * 8];

  floatx4 s[20];
  #pragma unroll
  for (int kt = 0; kt < 20; kt++) {
    bf16x8 b0 = *(const bf16x8*)&KV[(kt * 16 + c) * 72 + quad * 8];
    bf16x8 b1 = *(const bf16x8*)&KV[(kt * 16 + c) * 72 + 32 + quad * 8];
    floatx4 t = (floatx4){0.f, 0.f, 0.f, 0.f};
    t = __builtin_amdgcn_mfma_f32_16x16x32_bf16(aq[0], b0, t, 0, 0, 0);
    t = __builtin_amdgcn_mfma_f32_16x16x32_bf16(aq[1], b1, t, 0, 0, 0);
    s[kt] = t;
  }
  __syncthreads();

  for (int ch = wave; ch < 5; ch += 4) {
    int koff = ch * 64 + lane;
    int kg = qBase - 127 + koff;
    int kgc = min(max(kg, 0), T_SEQ - 1);
    const unsigned short* vrow = Vg + hbase + (size_t)kgc * DHEAD;
    #pragma unroll
    for (int dg = 0; dg < 8; dg++) {
      bf16x8 v8 = *(const bf16x8*)(vrow + dg * 8);
      #pragma unroll
      for (int j = 0; j < 8; j++)
        KV[(dg * 8 + j) * 328 + koff] = (unsigned short)v8[j];
    }
  }

  const int kLoMin = max(0, 127 - qBase);
  const int kHiMax = min(319, 2047 + 127 - qBase);
  float mx[4] = {-3e38f, -3e38f, -3e38f, -3e38f};
  #pragma unroll
  for (int kt = 0; kt < 20; kt++) {
    const int koff = kt * 16 + c;
    #pragma unroll
    for (int reg = 0; reg < 4; reg++) {
      const int qrow = wave * 16 + quad * 4 + reg;
      const int d = koff - qrow;
      bool ok = (d >= 0) && (d <= 255) && (koff >= kLoMin) && (koff <= kHiMax);
      float val = ok ? s[kt][reg] * 0.125f : -3e38f;
      s[kt][reg] = val;
      mx[reg] = fmaxf(mx[reg], val);
    }
  }
  #pragma unroll
  for (int reg = 0; reg < 4; reg++)
    #pragma unroll
    for (int m = 1; m <= 8; m <<= 1)
      mx[reg] = fmaxf(mx[reg], __shfl_xor(mx[reg], m));

  float ls[4] = {0.f, 0.f, 0.f, 0.f};
  #pragma unroll
  for (int kt = 0; kt < 20; kt++) {
    const int koff = kt * 16 + c;
    #pragma unroll
    for (int reg = 0; reg < 4; reg++) {
      float p = __expf(s[kt][reg] - mx[reg]);
      ls[reg] += p;
      Ps[wave * 5248 + (quad * 4 + reg) * 328 + koff] = f2bf(p);
    }
  }
  float inv[4];
  #pragma unroll
  for (int reg = 0; reg < 4; reg++) {
    #pragma unroll
    for (int m = 1; m <= 8; m <<= 1) ls[reg] += __shfl_xor(ls[reg], m);
    inv[reg] = 1.f / ls[reg];
  }
  __syncthreads();

  floatx4 oacc[4];
  #pragma unroll
  for (int nt = 0; nt < 4; nt++) oacc[nt] = (floatx4){0.f, 0.f, 0.f, 0.f};
  #pragma unroll
  for (int kt2 = 0; kt2 < 10; kt2++) {
    bf16x8 a = *(const bf16x8*)&Ps[wave * 5248 + c * 328 + kt2 * 32 + quad * 8];
    #pragma unroll
    for (int nt = 0; nt < 4; nt++) {
      bf16x8 bb = *(const bf16x8*)&KV[(nt * 16 + c) * 328 + kt2 * 32 + quad * 8];
      oacc[nt] = __builtin_amdgcn_mfma_f32_16x16x32_bf16(a, bb, oacc[nt], 0, 0, 0);
    }
  }

  const int b = bh >> 4, h = bh & 15;
  #pragma unroll
  for (int nt = 0; nt < 4; nt++) {
    #pragma unroll
    for (int reg = 0; reg < 4; reg++) {
      const int qg = qBase + wave * 16 + quad * 4 + reg;
      Og[((size_t)(b * T_SEQ + qg)) * DMODEL + h * DHEAD + nt * 16 + c] =
          f2bf(oacc[nt][reg] * inv[reg]);
    }
  }
}

// ---------------------------------------------------------------------------
// x2 = rmsnorm(a + ALPHA*x, g1) (unchanged).
// ---------------------------------------------------------------------------
__global__ __launch_bounds__(256) void rmsnorm_mid(
    const unsigned short* __restrict__ a,
    const float* __restrict__ x,
    const float* __restrict__ g,
    unsigned short* __restrict__ out)
{
  __shared__ float red[4];
  const int row = blockIdx.x;
  const int tid = threadIdx.x;
  const size_t base = (size_t)row * DMODEL;
  const int c = tid * 4;
  bf16x4  av = *(const bf16x4*)(a + base + c);
  floatx4 xv = *(const floatx4*)(x + base + c);
  floatx4 gv = *(const floatx4*)(g + c);
  float s[4], ss = 0.f;
  #pragma unroll
  for (int j = 0; j < 4; j++) {
    s[j] = bf2f((unsigned short)av[j]) + ALPHA_C * xv[j];
    ss += s[j] * s[j];
  }
  #pragma unroll
  for (int m = 1; m <= 32; m <<= 1) ss += __shfl_xor(ss, m);
  if ((tid & 63) == 0) red[tid >> 6] = ss;
  __syncthreads();
  float ms = (red[0] + red[1] + red[2] + red[3]) * (1.f / DMODEL);
  float scl = rsqrtf(ms + EPS_C);
  bf16x4 ov;
  #pragma unroll
  for (int j = 0; j < 4; j++) ov[j] = (short)f2bf(s[j] * scl * gv[j]);
  *(bf16x4*)(out + base + c) = ov;
}

// ---------------------------------------------------------------------------
// out = rmsnorm(y2 + ALPHA*x2, g2): single f32 input (unchanged).
// ---------------------------------------------------------------------------
__global__ __launch_bounds__(256) void rmsnorm_final(
    const float* __restrict__ y2,
    const unsigned short* __restrict__ x2,
    const float* __restrict__ g,
    float* __restrict__ out)
{
  __shared__ float red[4];
  const int row = blockIdx.x;
  const int tid = threadIdx.x;
  const size_t base = (size_t)row * DMODEL;
  const int c = tid * 4;
  floatx4 a0 = *(const floatx4*)(y2 + base + c);
  bf16x4  xv = *(const bf16x4*)(x2 + base + c);
  floatx4 gv = *(const floatx4*)(g + c);
  float s[4], ss = 0.f;
  #pragma unroll
  for (int j = 0; j < 4; j++) {
    s[j] = a0[j] + ALPHA_C * bf2f((unsigned short)xv[j]);
    ss += s[j] * s[j];
  }
  #pragma unroll
  for (int m = 1; m <= 32; m <<= 1) ss += __shfl_xor(ss, m);
  if ((tid & 63) == 0) red[tid >> 6] = ss;
  __syncthreads();
  float ms = (red[0] + red[1] + red[2] + red[3]) * (1.f / DMODEL);
  float scl = rsqrtf(ms + EPS_C);
  floatx4 ov;
  #pragma unroll
  for (int j = 0; j < 4; j++) ov[j] = s[j] * scl * gv[j];
  *(floatx4*)(out + base + c) = ov;
}

// ---------------------------------------------------------------------------
// Workspace layout unchanged.
// ---------------------------------------------------------------------------
extern "C" void kernel_launch(void* const* d_in, const int* in_sizes, int n_in,
                              void* d_out, int out_size, void* d_ws, size_t ws_size,
                              hipStream_t stream) {
  (void)in_sizes; (void)n_in; (void)out_size; (void)ws_size;
  const float* x    = (const float*)d_in[0];
  const float* Wqkv = (const float*)d_in[1];
  const float* Wout = (const float*)d_in[2];
  const float* bout = (const float*)d_in[3];
  const float* W1   = (const float*)d_in[4];
  const float* W2   = (const float*)d_in[5];
  const float* g1   = (const float*)d_in[6];
  const float* g2   = (const float*)d_in[7];
  float* out = (float*)d_out;

  unsigned short* ws    = (unsigned short*)d_ws;
  unsigned short* Wqkvb = ws;
  unsigned short* Woutb = ws + 3145728;
  unsigned short* W1b   = ws + 4194304;
  unsigned short* W2b   = ws + 12582912;
  unsigned short* P1    = ws + 16777216;
  unsigned short* x2    = ws + 20971520;
  unsigned short* q     = ws + 25165824;
  unsigned short* k     = ws + 29360128;
  unsigned short* v     = ws + 33554432;
  unsigned short* o     = ws + 37748736;
  unsigned short* ys    = ws + 25165824;         // q/k/v dead after attn
  float* cosT = (float*)(ws + 37748736);         // LUT overlays o (dead then)
  float* sinT = cosT + 65536;
  float* y2f  = (float*)(ws + 41943040);         // 4096*1024 f32

  // 0. merged f32->bf16 conversion + RoPE LUT (one launch)
  convert_all<<<10496, 256, 0, stream>>>(Wqkv, Wout, W1, W2, x, ws, cosT, sinT);
  // 1. qkv GEMM + fused RoPE/split -> q,k,v  (depth-2 split-lgkm 4-phase)
  gemm_qkv_rope256<<<192, 512, 0, stream>>>(P1, Wqkvb, cosT, sinT, q, k, v);
  // 2. MFMA banded attention -> o [B,T,1024]
  attn_mfma<<<32 * (T_SEQ / 64), 256, 0, stream>>>(q, k, v, o);
  // 3. a = o @ Wout^T + bout -> P1  (2-phase 256-tile template)
  gemm_wout_2ph<<<128, 512, 0, stream>>>(o, Woutb, bout, P1);
  // 4. x2 = rmsnorm(a + ALPHA*x, g1)
  rmsnorm_mid<<<4096, 256, 0, stream>>>(P1, x, g1, x2);
  // 5. W1 GEMM + fused SwiGLU -> ys  (depth-2 split-lgkm 4-phase)
  gemm_w1_swiglu_s4<<<512, 512, 0, stream>>>(x2, W1b, ys);
  // 6. y2 = ys @ W2^T single-pass K=4096 -> y2 f32
  gemm_w2_1k<<<256, 512, 0, stream>>>(ys, W2b, y2f);
  // 7. out = rmsnorm(y2 + ALPHA*x2, g2)
  rmsnorm_final<<<4096, 256, 0, stream>>>(y2f, x2, g2, out);
}

// Round 11
// 343.736 us; speedup vs baseline: 1.0567x; 1.0567x over previous
//
#include <hip/hip_runtime.h>

#define T_SEQ   2048
#define NHEADS  16
#define DHEAD   64
#define DMODEL  1024
#define ALPHA_C 1.4142135f
#define EPS_C   1e-5f

typedef __attribute__((ext_vector_type(8))) short bf16x8;
typedef __attribute__((ext_vector_type(4))) short bf16x4;
typedef __attribute__((ext_vector_type(4))) float floatx4;

__device__ __forceinline__ float bf2f(unsigned short u) {
  union { unsigned int i; float f; } v;
  v.i = ((unsigned int)u) << 16;
  return v.f;
}
__device__ __forceinline__ unsigned short f2bf(float f) {
  union { float f; unsigned int i; } v;
  v.f = f;
  unsigned int u = v.i;
  u += 0x7FFF + ((u >> 16) & 1);   // RNE (finite data only)
  return (unsigned short)(u >> 16);
}

__device__ __forceinline__ void gload_lds16(const void* g, void* l) {
  __builtin_amdgcn_global_load_lds(
      (const __attribute__((address_space(1))) void*)g,
      (__attribute__((address_space(3))) void*)l, 16, 0, 0);
}

// ---------------------------------------------------------------------------
// Merged f32->bf16 convert of all 5 inputs + RoPE LUT (one launch).
// ---------------------------------------------------------------------------
__global__ void convert_all(const float* __restrict__ Wqkv,
                            const float* __restrict__ Wout,
                            const float* __restrict__ W1,
                            const float* __restrict__ W2,
                            const float* __restrict__ x,
                            unsigned short* __restrict__ ws,
                            float* __restrict__ cosT,
                            float* __restrict__ sinT)
{
  if (blockIdx.x >= 10240) {                    // RoPE LUT tail blocks
    int gid = (blockIdx.x - 10240) * 256 + threadIdx.x;
    int t = gid >> 5, i = gid & 31;
    float fr = powf(10000.f, -(float)i * (1.f / 32.f));
    float sn, cs;
    sincosf((float)t * fr, &sn, &cs);
    cosT[gid] = cs;
    sinT[gid] = sn;
    return;
  }
  size_t i = ((size_t)blockIdx.x * 256 + threadIdx.x) * 8;
  const float* src;
  size_t off;
  if      (i <  3145728) { src = Wqkv; off = i; }
  else if (i <  4194304) { src = Wout; off = i -  3145728; }
  else if (i < 12582912) { src = W1;   off = i -  4194304; }
  else if (i < 16777216) { src = W2;   off = i - 12582912; }
  else                   { src = x;    off = i - 16777216; }
  floatx4 a = *(const floatx4*)(src + off);
  floatx4 b = *(const floatx4*)(src + off + 4);
  bf16x8 o;
  #pragma unroll
  for (int u = 0; u < 4; u++) {
    o[u]     = (short)f2bf(a[u]);
    o[4 + u] = (short)f2bf(b[u]);
  }
  *(bf16x8*)(ws + i) = o;
}

// ---------------------------------------------------------------------------
// 256-tile split-lgkm 4-phase template, depth-2 staging (unchanged).
// ---------------------------------------------------------------------------
#define BAR() __builtin_amdgcn_s_barrier()
#define SCB() __builtin_amdgcn_sched_barrier(0)

#define RD_A_S(bb, mh, s)                                                 \
  _Pragma("unroll") for (int i = 0; i < 4; i++)                           \
    af[i][s] = *(const bf16x8*)&lds[(bb) + aRd +                          \
        ((mh) * 64 + i * 16 + mrow) * 64 + (kq0 ^ ((s) << 5))];

#define RD_B_S(bb, s)                                                     \
  _Pragma("unroll") for (int n = 0; n < 4; n++)                           \
    bfr[n][s] = *(const bf16x8*)&lds[(bb) + bRd +                         \
        (bRow0 + n * 16 + mrow) * 64 + (kq0 ^ ((s) << 5))];

#define MFMA8(mh, nh, s)                                                  \
  _Pragma("unroll") for (int i = 0; i < 4; i++)                           \
  _Pragma("unroll") for (int n = 0; n < 2; n++)                           \
    acc[(mh) * 4 + i][(nh) * 2 + n] =                                     \
        __builtin_amdgcn_mfma_f32_16x16x32_bf16(                          \
            af[i][s], bfr[(nh) * 2 + n][s],                               \
            acc[(mh) * 4 + i][(nh) * 2 + n], 0, 0, 0);

#define KLOOP_S4()                                                        \
  for (int t = 0; t < 16; ++t) {                                          \
    const int cur = t & 1;                                                \
    const int bb  = cur * 32768;                                          \
    const int tb  = (t + 2 < 16) ? t + 2 : 15;                            \
    /* phase 1: reads a0 + all B (split 8/0), no stage */                 \
    BAR();                                                                \
    RD_A_S(bb, 0, 0); RD_B_S(bb, 0);                                      \
    SCB();                                                                \
    RD_A_S(bb, 0, 1); RD_B_S(bb, 1);                                      \
    asm volatile("s_waitcnt lgkmcnt(8)" ::: "memory");                    \
    SCB();                                                                \
    __builtin_amdgcn_s_setprio(1);                                        \
    MFMA8(0, 0, 0);                                                       \
    __builtin_amdgcn_s_setprio(0);                                        \
    asm volatile("s_waitcnt lgkmcnt(0)" ::: "memory");                    \
    SCB();                                                                \
    __builtin_amdgcn_s_setprio(1);                                        \
    MFMA8(0, 0, 1);                                                       \
    __builtin_amdgcn_s_setprio(0);                                        \
    /* phase 2: stage B[cur]<-t+2 (4 gl), pure MFMA */                    \
    BAR();                                                                \
    stB(cur, 0, tb); stB(cur, 1, tb);                                     \
    __builtin_amdgcn_s_setprio(1);                                        \
    MFMA8(0, 1, 0); MFMA8(0, 1, 1);                                       \
    __builtin_amdgcn_s_setprio(0);                                        \
    /* phase 3: reads a1 (split 4/0), no stage */                         \
    BAR();                                                                \
    RD_A_S(bb, 1, 0);                                                     \
    SCB();                                                                \
    RD_A_S(bb, 1, 1);                                                     \
    asm volatile("s_waitcnt lgkmcnt(4)" ::: "memory");                    \
    SCB();                                                                \
    __builtin_amdgcn_s_setprio(1);                                        \
    MFMA8(1, 1, 0);                                                       \
    __builtin_amdgcn_s_setprio(0);                                        \
    asm volatile("s_waitcnt lgkmcnt(0)" ::: "memory");                    \
    SCB();                                                                \
    __builtin_amdgcn_s_setprio(1);                                        \
    MFMA8(1, 1, 1);                                                       \
    __builtin_amdgcn_s_setprio(0);                                        \
    /* phase 4: stage A[cur]<-t+2 (4 gl), pure MFMA, vmcnt(8) */          \
    BAR();                                                                \
    stA(cur, 0, tb); stA(cur, 1, tb);                                     \
    __builtin_amdgcn_s_setprio(1);                                        \
    MFMA8(1, 0, 0); MFMA8(1, 0, 1);                                       \
    __builtin_amdgcn_s_setprio(0);                                        \
    asm volatile("s_waitcnt vmcnt(8)" ::: "memory");                      \
  }

// ---------------------------------------------------------------------------
// W1 GEMM + fused SwiGLU — depth-2 split-lgkm schedule (unchanged).
// ---------------------------------------------------------------------------
__global__ __launch_bounds__(512, 2) void gemm_w1_swiglu_s4(
    const unsigned short* __restrict__ A,    // x2 [4096][1024]
    const unsigned short* __restrict__ W1,   // [8192][1024]
    unsigned short* __restrict__ ys)         // [4096][4096]
{
  __shared__ unsigned short lds[65536];

  const int tid  = threadIdx.x;
  const int lane = tid & 63;
  const int wid  = tid >> 6;
  const int wr   = wid >> 2;     // M half
  const int wc   = wid & 3;      // N quarter
  const int mrow = lane & 15;
  const int quad = lane >> 4;
  const int kq0  = (quad ^ (mrow & 7)) * 8;   // full st-swizzle

  const int bid  = blockIdx.x;
  const int c8   = bid & 7;
  const int u    = bid >> 3;     // 0..63
  const int mBase = ((c8 >> 2) * 8 + (u >> 3)) * 256;
  const int nBase = ((c8 &  3) * 8 + (u &  7)) * 128;

  const int r0 = tid >> 3;
  const int ce = (((tid & 7) ^ (r0 & 7)) * 8);
  const size_t aoff0 = (size_t)(mBase + r0) * 1024 + ce;
  const size_t aoff1 = aoff0 + (size_t)64 * 1024;
  auto growf = [&](int br) {
    int col = nBase + (br >> 6) * 32 + (br & 31);
    return ((br >> 5) & 1) ? 4096 + col : col;
  };
  const size_t boff00 = (size_t)growf(r0)       * 1024 + ce;
  const size_t boff01 = (size_t)growf(64 + r0)  * 1024 + ce;
  const size_t boff10 = (size_t)growf(128 + r0) * 1024 + ce;
  const size_t boff11 = (size_t)growf(192 + r0) * 1024 + ce;
  const int d0 = tid * 8;

  auto stA = [&](int buf, int h, int kt) {
    const unsigned short* g = A + (size_t)kt * 64 + (h ? (size_t)128 * 1024 : 0);
    int base = buf * 32768 + h * 8192;
    gload_lds16(g + aoff0, &lds[base + d0]);
    gload_lds16(g + aoff1, &lds[base + 4096 + d0]);
  };
  auto stB = [&](int buf, int h, int kt) {
    const unsigned short* g = W1 + (size_t)kt * 64;
    int base = buf * 32768 + 16384 + h * 8192;
    gload_lds16(g + (h ? boff10 : boff00), &lds[base + d0]);
    gload_lds16(g + (h ? boff11 : boff01), &lds[base + 4096 + d0]);
  };

  floatx4 acc[8][4];
  #pragma unroll
  for (int i = 0; i < 8; i++)
    #pragma unroll
    for (int n = 0; n < 4; n++) acc[i][n] = (floatx4){0.f, 0.f, 0.f, 0.f};
  bf16x8 af[4][2], bfr[4][2];

  const int aRd   = wr * 8192;
  const int bRd   = 16384 + (wc >> 1) * 8192;
  const int bRow0 = (wc & 1) * 64;

  // prologue: full tile0 + full tile1 (16 gloads); vmcnt(8) drains tile0
  stB(0, 0, 0); stB(0, 1, 0); stA(0, 0, 0); stA(0, 1, 0);
  stB(1, 0, 1); stB(1, 1, 1); stA(1, 0, 1); stA(1, 1, 1);
  asm volatile("s_waitcnt vmcnt(8)" ::: "memory");

  KLOOP_S4();

  // epilogue: SwiGLU in-register (y = acc[][n], gate = acc[][n+2])
  const int col0 = lane & 15;
  const int row0 = (lane >> 4) * 4;
  #pragma unroll
  for (int n = 0; n < 2; n++) {
    const int col = nBase + wc * 32 + n * 16 + col0;
    #pragma unroll
    for (int i = 0; i < 8; i++) {
      const int rowb = mBase + wr * 128 + i * 16 + row0;
      #pragma unroll
      for (int r = 0; r < 4; r++) {
        float y = acc[i][n][r], g = acc[i][n + 2][r];
        float sig = 1.f / (1.f + __expf(-g));
        ys[(size_t)(rowb + r) * 4096 + col] = f2bf(y * g * sig);
      }
    }
  }
  asm volatile("s_waitcnt vmcnt(0)" ::: "memory");
}

// ---------------------------------------------------------------------------
// qkv GEMM + fused RoPE, depth-2 split-lgkm schedule (unchanged).
// ---------------------------------------------------------------------------
__global__ __launch_bounds__(512, 2) void gemm_qkv_rope256(
    const unsigned short* __restrict__ A,    // xb [4096][1024]
    const unsigned short* __restrict__ W,    // Wqkv [3072][1024]
    const float* __restrict__ cosT,
    const float* __restrict__ sinT,
    unsigned short* __restrict__ Qd,
    unsigned short* __restrict__ Kd,
    unsigned short* __restrict__ Vd)
{
  __shared__ unsigned short lds[65536];

  const int tid  = threadIdx.x;
  const int lane = tid & 63;
  const int wid  = tid >> 6;
  const int wr   = wid >> 2;     // M half
  const int wc   = wid & 3;      // N quarter (one 64-col head)
  const int mrow = lane & 15;
  const int quad = lane >> 4;
  const int kq0  = (quad ^ (mrow & 7)) * 8;

  // XCD map over 192 blocks: bijective.
  const int bid  = blockIdx.x;
  const int c8   = bid & 7;
  const int u    = bid >> 3;
  const int mBase = ((c8 >> 1) * 4 + u / 6) * 256;
  const int nBase = ((c8 & 1) * 6 + u % 6) * 256;

  const int r0 = tid >> 3;
  const int ce = (((tid & 7) ^ (r0 & 7)) * 8);
  const size_t aoff0 = (size_t)(mBase + r0) * 1024 + ce;
  const size_t aoff1 = aoff0 + (size_t)64 * 1024;
  const size_t boff00 = (size_t)(nBase + r0)       * 1024 + ce;
  const size_t boff01 = (size_t)(nBase + 64 + r0)  * 1024 + ce;
  const size_t boff10 = (size_t)(nBase + 128 + r0) * 1024 + ce;
  const size_t boff11 = (size_t)(nBase + 192 + r0) * 1024 + ce;
  const int d0 = tid * 8;

  auto stA = [&](int buf, int h, int kt) {
    const unsigned short* g = A + (size_t)kt * 64 + (h ? (size_t)128 * 1024 : 0);
    int base = buf * 32768 + h * 8192;
    gload_lds16(g + aoff0, &lds[base + d0]);
    gload_lds16(g + aoff1, &lds[base + 4096 + d0]);
  };
  auto stB = [&](int buf, int h, int kt) {
    const unsigned short* g = W + (size_t)kt * 64;
    int base = buf * 32768 + 16384 + h * 8192;
    gload_lds16(g + (h ? boff10 : boff00), &lds[base + d0]);
    gload_lds16(g + (h ? boff11 : boff01), &lds[base + 4096 + d0]);
  };

  floatx4 acc[8][4];
  #pragma unroll
  for (int i = 0; i < 8; i++)
    #pragma unroll
    for (int n = 0; n < 4; n++) acc[i][n] = (floatx4){0.f, 0.f, 0.f, 0.f};
  bf16x8 af[4][2], bfr[4][2];

  const int aRd   = wr * 8192;
  const int bRd   = 16384 + (wc >> 1) * 8192;
  const int bRow0 = (wc & 1) * 64;

  // prologue: full tile0 + full tile1; vmcnt(8) drains tile0
  stB(0, 0, 0); stB(0, 1, 0); stA(0, 0, 0); stA(0, 1, 0);
  stB(1, 0, 1); stB(1, 1, 1); stA(1, 0, 1); stA(1, 1, 1);
  asm volatile("s_waitcnt vmcnt(8)" ::: "memory");

  KLOOP_S4();

  // ---- epilogue: RoPE (q,k) / plain store (v) ----
  const int col0 = lane & 15;
  const int row0 = (lane >> 4) * 4;
  const int colBase = nBase + wc * 64;     // wave-uniform, one head
  const int sect = colBase >> 10;          // 0=q, 1=k, 2=v
  const int h    = (colBase & 1023) >> 6;  // head index
  unsigned short* dst = (sect == 0) ? Qd : (sect == 1) ? Kd : Vd;

  if (sect < 2) {
    #pragma unroll
    for (int i = 0; i < 8; i++) {
      #pragma unroll
      for (int r = 0; r < 4; r++) {
        const int row = mBase + wr * 128 + i * 16 + row0 + r;
        const int b = row >> 11, t = row & 2047;
        size_t ob = ((size_t)((b * NHEADS + h) * T_SEQ + t)) * DHEAD;
        const int tb = t * 32;
        float c0 = cosT[tb + col0],      s0 = sinT[tb + col0];
        float c1 = cosT[tb + col0 + 16], s1 = sinT[tb + col0 + 16];
        float x1a = acc[i][0][r], x2a = acc[i][2][r];
        float x1b = acc[i][1][r], x2b = acc[i][3][r];
        dst[ob + col0]      = f2bf(x1a * c0 - x2a * s0);
        dst[ob + col0 + 32] = f2bf(x2a * c0 + x1a * s0);
        dst[ob + col0 + 16] = f2bf(x1b * c1 - x2b * s1);
        dst[ob + col0 + 48] = f2bf(x2b * c1 + x1b * s1);
      }
    }
  } else {
    #pragma unroll
    for (int i = 0; i < 8; i++)
      #pragma unroll
      for (int n = 0; n < 4; n++)
        #pragma unroll
        for (int r = 0; r < 4; r++) {
          const int row = mBase + wr * 128 + i * 16 + row0 + r;
          const int b = row >> 11, t = row & 2047;
          dst[((size_t)((b * NHEADS + h) * T_SEQ + t)) * DHEAD + n * 16 + col0] =
              f2bf(acc[i][n][r]);
        }
  }
  asm volatile("s_waitcnt vmcnt(0)" ::: "memory");
}

// ---------------------------------------------------------------------------
// Shared 2-phase 256x128 template macros (w2 / wout).
// ---------------------------------------------------------------------------
#define W2_RD_A(bb, mh, s)                                                \
  _Pragma("unroll") for (int i = 0; i < 2; i++)                           \
    af[i][s] = *(const bf16x8*)&lds[(bb) +                                \
        (wr * 64 + (mh) * 32 + i * 16 + mrow) * 64 + (kq0 ^ ((s) << 5))];

#define W2_RD_B(bb, s)                                                    \
  _Pragma("unroll") for (int n = 0; n < 4; n++)                           \
    bfr[n][s] = *(const bf16x8*)&lds[(bb) + 16384 +                       \
        (wc * 64 + n * 16 + mrow) * 64 + (kq0 ^ ((s) << 5))];

#define W2_MFMA(mh, s)                                                    \
  _Pragma("unroll") for (int i = 0; i < 2; i++)                           \
  _Pragma("unroll") for (int n = 0; n < 4; n++)                           \
    acc[(mh) * 2 + i][n] =                                                \
        __builtin_amdgcn_mfma_f32_16x16x32_bf16(                          \
            af[i][s], bfr[n][s], acc[(mh) * 2 + i][n], 0, 0, 0);

#define W2_KLOOP(NT)                                                      \
  for (int t = 0; t < (NT); ++t) {                                        \
    const int cur = t & 1;                                                \
    const int nxt = cur ^ 1;                                              \
    const int bb  = cur * 24576;                                          \
    const int ta  = (t + 1 < (NT)) ? t + 1 : (NT) - 1;                    \
    const int tb  = (t + 2 < (NT)) ? t + 2 : (NT) - 1;                    \
    BAR();                                                                \
    stA(nxt, 0, ta); stA(nxt, 1, ta);                                     \
    W2_RD_A(bb, 0, 0); W2_RD_B(bb, 0);                                    \
    SCB();                                                                \
    W2_RD_A(bb, 0, 1); W2_RD_B(bb, 1);                                    \
    asm volatile("s_waitcnt lgkmcnt(6)" ::: "memory");                    \
    SCB();                                                                \
    __builtin_amdgcn_s_setprio(1);                                        \
    W2_MFMA(0, 0);                                                        \
    __builtin_amdgcn_s_setprio(0);                                        \
    asm volatile("s_waitcnt lgkmcnt(0)" ::: "memory");                    \
    SCB();                                                                \
    __builtin_amdgcn_s_setprio(1);                                        \
    W2_MFMA(0, 1);                                                        \
    __builtin_amdgcn_s_setprio(0);                                        \
    BAR();                                                                \
    stB(cur, tb);                                                         \
    W2_RD_A(bb, 1, 0);                                                    \
    SCB();                                                                \
    W2_RD_A(bb, 1, 1);                                                    \
    asm volatile("s_waitcnt lgkmcnt(2)" ::: "memory");                    \
    SCB();                                                                \
    __builtin_amdgcn_s_setprio(1);                                        \
    W2_MFMA(1, 0);                                                        \
    __builtin_amdgcn_s_setprio(0);                                        \
    asm volatile("s_waitcnt lgkmcnt(0)" ::: "memory");                    \
    SCB();                                                                \
    __builtin_amdgcn_s_setprio(1);                                        \
    W2_MFMA(1, 1);                                                        \
    __builtin_amdgcn_s_setprio(0);                                        \
    asm volatile("s_waitcnt vmcnt(2)" ::: "memory");                      \
  }

// ---------------------------------------------------------------------------
// W2 split-K GEMM, 2-phase 256-tile template (REVERT to round-8 version —
// single-pass BN=64 variant measured +17 us: 1.67x VMEM issue traffic +
// uncovered mid-tile prefetch).
// ---------------------------------------------------------------------------
__global__ __launch_bounds__(512, 2) void gemm_w2_2ph(
    const unsigned short* __restrict__ A,    // ys [4096][4096]
    const unsigned short* __restrict__ W,    // W2 [1024][4096]
    float* __restrict__ Cp)                  // [2][4096][1024] partials
{
  __shared__ unsigned short lds[49152];      // 2 x 24576 (A 16384 + B 8192)

  const int tid  = threadIdx.x;
  const int lane = tid & 63;
  const int wid  = tid >> 6;
  const int wr   = wid >> 1;     // M quarter
  const int wc   = wid & 1;      // N half
  const int mrow = lane & 15;
  const int quad = lane >> 4;
  const int kq0  = (quad ^ (mrow & 7)) * 8;

  const int u  = blockIdx.x;
  const int c8 = u & 7;
  const int v  = u >> 3;
  const int zP = v >> 4;
  const int mBase = (((c8 >> 1) & 3) * 4 + ((v >> 2) & 3)) * 256;
  const int nBase = ((c8 & 1) * 4 + (v & 3)) * 128;
  const int kOff  = zP * 2048;

  const int r0 = tid >> 3;
  const int ce = (((tid & 7) ^ (r0 & 7)) * 8);
  const int d0 = tid * 8;

  auto stA = [&](int buf, int h, int kt) {
    const unsigned short* g =
        A + (size_t)(mBase + h * 128 + r0) * 4096 + kOff + kt * 64 + ce;
    int base = buf * 24576 + h * 8192;
    gload_lds16(g, &lds[base + d0]);
    gload_lds16(g + (size_t)64 * 4096, &lds[base + 4096 + d0]);
  };
  auto stB = [&](int buf, int kt) {
    const unsigned short* g =
        W + (size_t)(nBase + r0) * 4096 + kOff + kt * 64 + ce;
    int base = buf * 24576 + 16384;
    gload_lds16(g, &lds[base + d0]);
    gload_lds16(g + (size_t)64 * 4096, &lds[base + 4096 + d0]);
  };

  floatx4 acc[4][4];
  #pragma unroll
  for (int i = 0; i < 4; i++)
    #pragma unroll
    for (int n = 0; n < 4; n++) acc[i][n] = (floatx4){0.f, 0.f, 0.f, 0.f};
  bf16x8 af[2][2], bfr[4][2];

  stB(0, 0);
  stA(0, 0, 0); stA(0, 1, 0);
  stB(1, 1);
  asm volatile("s_waitcnt vmcnt(2)" ::: "memory");

  W2_KLOOP(32);

  const int col0 = lane & 15;
  const int row0 = (lane >> 4) * 4;
  float* dst = Cp + (size_t)zP * 4096 * 1024;
  #pragma unroll
  for (int n = 0; n < 4; n++) {
    const int col = nBase + wc * 64 + n * 16 + col0;
    #pragma unroll
    for (int i = 0; i < 4; i++) {
      const int rowb = mBase + wr * 64 + i * 16 + row0;
      #pragma unroll
      for (int r = 0; r < 4; r++)
        dst[(size_t)(rowb + r) * 1024 + col] = acc[i][n][r];
    }
  }
  asm volatile("s_waitcnt vmcnt(0)" ::: "memory");
}

// ---------------------------------------------------------------------------
// Wout projection, 2-phase template (unchanged).
// ---------------------------------------------------------------------------
__global__ __launch_bounds__(512, 2) void gemm_wout_2ph(
    const unsigned short* __restrict__ A,    // o [4096][1024]
    const unsigned short* __restrict__ W,    // Wout [1024][1024]
    const float* __restrict__ bias,          // bout [1024]
    unsigned short* __restrict__ C)          // P1 [4096][1024]
{
  __shared__ unsigned short lds[49152];      // 2 x 24576 (A 16384 + B 8192)

  const int tid  = threadIdx.x;
  const int lane = tid & 63;
  const int wid  = tid >> 6;
  const int wr   = wid >> 1;     // M quarter
  const int wc   = wid & 1;      // N half
  const int mrow = lane & 15;
  const int quad = lane >> 4;
  const int kq0  = (quad ^ (mrow & 7)) * 8;

  const int u  = blockIdx.x;
  const int c8 = u & 7;
  const int v  = u >> 3;                     // 0..15
  const int mBase = ((c8 >> 1) * 4 + (v >> 2)) * 256;
  const int nBase = ((c8 & 1) * 4 + (v & 3)) * 128;

  const int r0 = tid >> 3;
  const int ce = (((tid & 7) ^ (r0 & 7)) * 8);
  const int d0 = tid * 8;

  auto stA = [&](int buf, int h, int kt) {
    const unsigned short* g =
        A + (size_t)(mBase + h * 128 + r0) * 1024 + kt * 64 + ce;
    int base = buf * 24576 + h * 8192;
    gload_lds16(g, &lds[base + d0]);
    gload_lds16(g + (size_t)64 * 1024, &lds[base + 4096 + d0]);
  };
  auto stB = [&](int buf, int kt) {
    const unsigned short* g =
        W + (size_t)(nBase + r0) * 1024 + kt * 64 + ce;
    int base = buf * 24576 + 16384;
    gload_lds16(g, &lds[base + d0]);
    gload_lds16(g + (size_t)64 * 1024, &lds[base + 4096 + d0]);
  };

  floatx4 acc[4][4];
  #pragma unroll
  for (int i = 0; i < 4; i++)
    #pragma unroll
    for (int n = 0; n < 4; n++) acc[i][n] = (floatx4){0.f, 0.f, 0.f, 0.f};
  bf16x8 af[2][2], bfr[4][2];

  stB(0, 0);
  stA(0, 0, 0); stA(0, 1, 0);
  stB(1, 1);
  asm volatile("s_waitcnt vmcnt(2)" ::: "memory");

  W2_KLOOP(16);

  const int col0 = lane & 15;
  const int row0 = (lane >> 4) * 4;
  #pragma unroll
  for (int n = 0; n < 4; n++) {
    const int col = nBase + wc * 64 + n * 16 + col0;
    const float badd = bias[col];
    #pragma unroll
    for (int i = 0; i < 4; i++) {
      const int rowb = mBase + wr * 64 + i * 16 + row0;
      #pragma unroll
      for (int r = 0; r < 4; r++)
        C[(size_t)(rowb + r) * 1024 + col] = f2bf(acc[i][n][r] + badd);
    }
  }
  asm volatile("s_waitcnt vmcnt(0)" ::: "memory");
}

// ---------------------------------------------------------------------------
// MFMA banded attention (unchanged).
// ---------------------------------------------------------------------------
__global__ __launch_bounds__(256) void attn_mfma(
    const unsigned short* __restrict__ Qg,
    const unsigned short* __restrict__ Kg,
    const unsigned short* __restrict__ Vg,
    unsigned short* __restrict__ Og)
{
  __shared__ unsigned short KV[23040];   // K tile [320][72]; then V^T [64][328]
  __shared__ unsigned short Qs[64 * 72];
  __shared__ unsigned short Ps[4 * 16 * 328];

  const int tid  = threadIdx.x;
  const int lane = tid & 63;
  const int wave = tid >> 6;
  const int c    = lane & 15;
  const int quad = lane >> 4;
  const int blk  = blockIdx.x;
  const int bh   = blk >> 5;
  const int qBase = (blk & 31) * 64;
  const size_t hbase = (size_t)bh * T_SEQ * DHEAD;

  for (int e = tid; e < 320 * 8; e += 256) {
    int row = e >> 3, ch = e & 7;
    int kg = qBase - 127 + row;
    int kgc = min(max(kg, 0), T_SEQ - 1);
    *(bf16x8*)&KV[row * 72 + ch * 8] =
        *(const bf16x8*)(Kg + hbase + (size_t)kgc * DHEAD + ch * 8);
  }
  for (int e = tid; e < 64 * 8; e += 256) {
    int row = e >> 3, ch = e & 7;
    *(bf16x8*)&Qs[row * 72 + ch * 8] =
        *(const bf16x8*)(Qg + hbase + (size_t)(qBase + row) * DHEAD + ch * 8);
  }
  __syncthreads();

  bf16x8 aq[2];
  #pragma unroll
  for (int hh = 0; hh < 2; hh++)
    aq[hh] = *(const bf16x8*)&Qs[(wave * 16 + c) * 72 + hh * 32 + quad * 8];

  floatx4 s[20];
  #pragma unroll
  for (int kt = 0; kt < 20; kt++) {
    bf16x8 b0 = *(const bf16x8*)&KV[(kt * 16 + c) * 72 + quad * 8];
    bf16x8 b1 = *(const bf16x8*)&KV[(kt * 16 + c) * 72 + 32 + quad * 8];
    floatx4 t = (floatx4){0.f, 0.f, 0.f, 0.f};
    t = __builtin_amdgcn_mfma_f32_16x16x32_bf16(aq[0], b0, t, 0, 0, 0);
    t = __builtin_amdgcn_mfma_f32_16x16x32_bf16(aq[1], b1, t, 0, 0, 0);
    s[kt] = t;
  }
  __syncthreads();

  for (int ch = wave; ch < 5; ch += 4) {
    int koff = ch * 64 + lane;
    int kg = qBase - 127 + koff;
    int kgc = min(max(kg, 0), T_SEQ - 1);
    const unsigned short* vrow = Vg + hbase + (size_t)kgc * DHEAD;
    #pragma unroll
    for (int dg = 0; dg < 8; dg++) {
      bf16x8 v8 = *(const bf16x8*)(vrow + dg * 8);
      #pragma unroll
      for (int j = 0; j < 8; j++)
        KV[(dg * 8 + j) * 328 + koff] = (unsigned short)v8[j];
    }
  }

  const int kLoMin = max(0, 127 - qBase);
  const int kHiMax = min(319, 2047 + 127 - qBase);
  float mx[4] = {-3e38f, -3e38f, -3e38f, -3e38f};
  #pragma unroll
  for (int kt = 0; kt < 20; kt++) {
    const int koff = kt * 16 + c;
    #pragma unroll
    for (int reg = 0; reg < 4; reg++) {
      const int qrow = wave * 16 + quad * 4 + reg;
      const int d = koff - qrow;
      bool ok = (d >= 0) && (d <= 255) && (koff >= kLoMin) && (koff <= kHiMax);
      float val = ok ? s[kt][reg] * 0.125f : -3e38f;
      s[kt][reg] = val;
      mx[reg] = fmaxf(mx[reg], val);
    }
  }
  #pragma unroll
  for (int reg = 0; reg < 4; reg++)
    #pragma unroll
    for (int m = 1; m <= 8; m <<= 1)
      mx[reg] = fmaxf(mx[reg], __shfl_xor(mx[reg], m));

  float ls[4] = {0.f, 0.f, 0.f, 0.f};
  #pragma unroll
  for (int kt = 0; kt < 20; kt++) {
    const int koff = kt * 16 + c;
    #pragma unroll
    for (int reg = 0; reg < 4; reg++) {
      float p = __expf(s[kt][reg] - mx[reg]);
      ls[reg] += p;
      Ps[wave * 5248 + (quad * 4 + reg) * 328 + koff] = f2bf(p);
    }
  }
  float inv[4];
  #pragma unroll
  for (int reg = 0; reg < 4; reg++) {
    #pragma unroll
    for (int m = 1; m <= 8; m <<= 1) ls[reg] += __shfl_xor(ls[reg], m);
    inv[reg] = 1.f / ls[reg];
  }
  __syncthreads();

  floatx4 oacc[4];
  #pragma unroll
  for (int nt = 0; nt < 4; nt++) oacc[nt] = (floatx4){0.f, 0.f, 0.f, 0.f};
  #pragma unroll
  for (int kt2 = 0; kt2 < 10; kt2++) {
    bf16x8 a = *(const bf16x8*)&Ps[wave * 5248 + c * 328 + kt2 * 32 + quad * 8];
    #pragma unroll
    for (int nt = 0; nt < 4; nt++) {
      bf16x8 bb = *(const bf16x8*)&KV[(nt * 16 + c) * 328 + kt2 * 32 + quad * 8];
      oacc[nt] = __builtin_amdgcn_mfma_f32_16x16x32_bf16(a, bb, oacc[nt], 0, 0, 0);
    }
  }

  const int b = bh >> 4, h = bh & 15;
  #pragma unroll
  for (int nt = 0; nt < 4; nt++) {
    #pragma unroll
    for (int reg = 0; reg < 4; reg++) {
      const int qg = qBase + wave * 16 + quad * 4 + reg;
      Og[((size_t)(b * T_SEQ + qg)) * DMODEL + h * DHEAD + nt * 16 + c] =
          f2bf(oacc[nt][reg] * inv[reg]);
    }
  }
}

// ---------------------------------------------------------------------------
// x2 = rmsnorm(a + ALPHA*x, g1) (unchanged).
// ---------------------------------------------------------------------------
__global__ __launch_bounds__(256) void rmsnorm_mid(
    const unsigned short* __restrict__ a,
    const float* __restrict__ x,
    const float* __restrict__ g,
    unsigned short* __restrict__ out)
{
  __shared__ float red[4];
  const int row = blockIdx.x;
  const int tid = threadIdx.x;
  const size_t base = (size_t)row * DMODEL;
  const int c = tid * 4;
  bf16x4  av = *(const bf16x4*)(a + base + c);
  floatx4 xv = *(const floatx4*)(x + base + c);
  floatx4 gv = *(const floatx4*)(g + c);
  float s[4], ss = 0.f;
  #pragma unroll
  for (int j = 0; j < 4; j++) {
    s[j] = bf2f((unsigned short)av[j]) + ALPHA_C * xv[j];
    ss += s[j] * s[j];
  }
  #pragma unroll
  for (int m = 1; m <= 32; m <<= 1) ss += __shfl_xor(ss, m);
  if ((tid & 63) == 0) red[tid >> 6] = ss;
  __syncthreads();
  float ms = (red[0] + red[1] + red[2] + red[3]) * (1.f / DMODEL);
  float scl = rsqrtf(ms + EPS_C);
  bf16x4 ov;
  #pragma unroll
  for (int j = 0; j < 4; j++) ov[j] = (short)f2bf(s[j] * scl * gv[j]);
  *(bf16x4*)(out + base + c) = ov;
}

// ---------------------------------------------------------------------------
// out = rmsnorm((p0+p1) + ALPHA*x2, g2) (REVERT to split-K reducer).
// ---------------------------------------------------------------------------
__global__ __launch_bounds__(256) void rmsnorm_final_sk(
    const float* __restrict__ p0,
    const float* __restrict__ p1,
    const unsigned short* __restrict__ x2,
    const float* __restrict__ g,
    float* __restrict__ out)
{
  __shared__ float red[4];
  const int row = blockIdx.x;
  const int tid = threadIdx.x;
  const size_t base = (size_t)row * DMODEL;
  const int c = tid * 4;
  floatx4 a0 = *(const floatx4*)(p0 + base + c);
  floatx4 a1 = *(const floatx4*)(p1 + base + c);
  bf16x4  xv = *(const bf16x4*)(x2 + base + c);
  floatx4 gv = *(const floatx4*)(g + c);
  float s[4], ss = 0.f;
  #pragma unroll
  for (int j = 0; j < 4; j++) {
    s[j] = (a0[j] + a1[j]) + ALPHA_C * bf2f((unsigned short)xv[j]);
    ss += s[j] * s[j];
  }
  #pragma unroll
  for (int m = 1; m <= 32; m <<= 1) ss += __shfl_xor(ss, m);
  if ((tid & 63) == 0) red[tid >> 6] = ss;
  __syncthreads();
  float ms = (red[0] + red[1] + red[2] + red[3]) * (1.f / DMODEL);
  float scl = rsqrtf(ms + EPS_C);
  floatx4 ov;
  #pragma unroll
  for (int j = 0; j < 4; j++) ov[j] = s[j] * scl * gv[j];
  *(floatx4*)(out + base + c) = ov;
}

// ---------------------------------------------------------------------------
// Workspace layout (round-8 configuration).
// ---------------------------------------------------------------------------
extern "C" void kernel_launch(void* const* d_in, const int* in_sizes, int n_in,
                              void* d_out, int out_size, void* d_ws, size_t ws_size,
                              hipStream_t stream) {
  (void)in_sizes; (void)n_in; (void)out_size; (void)ws_size;
  const float* x    = (const float*)d_in[0];
  const float* Wqkv = (const float*)d_in[1];
  const float* Wout = (const float*)d_in[2];
  const float* bout = (const float*)d_in[3];
  const float* W1   = (const float*)d_in[4];
  const float* W2   = (const float*)d_in[5];
  const float* g1   = (const float*)d_in[6];
  const float* g2   = (const float*)d_in[7];
  float* out = (float*)d_out;

  unsigned short* ws    = (unsigned short*)d_ws;
  unsigned short* Wqkvb = ws;
  unsigned short* Woutb = ws + 3145728;
  unsigned short* W1b   = ws + 4194304;
  unsigned short* W2b   = ws + 12582912;
  unsigned short* P1    = ws + 16777216;
  unsigned short* x2    = ws + 20971520;
  unsigned short* q     = ws + 25165824;
  unsigned short* k     = ws + 29360128;
  unsigned short* v     = ws + 33554432;
  unsigned short* o     = ws + 37748736;
  unsigned short* ys    = ws + 25165824;         // q/k/v dead after attn
  float* cosT = (float*)(ws + 37748736);         // LUT overlays o (dead then)
  float* sinT = cosT + 65536;
  float* p0   = (float*)(ws + 41943040);         // 2 x 4096*1024 f32, contig

  // 0. merged f32->bf16 conversion + RoPE LUT (one launch)
  convert_all<<<10496, 256, 0, stream>>>(Wqkv, Wout, W1, W2, x, ws, cosT, sinT);
  // 1. qkv GEMM + fused RoPE/split -> q,k,v  (depth-2 split-lgkm 4-phase)
  gemm_qkv_rope256<<<192, 512, 0, stream>>>(P1, Wqkvb, cosT, sinT, q, k, v);
  // 2. MFMA banded attention -> o [B,T,1024]
  attn_mfma<<<32 * (T_SEQ / 64), 256, 0, stream>>>(q, k, v, o);
  // 3. a = o @ Wout^T + bout -> P1  (2-phase 256-tile template)
  gemm_wout_2ph<<<128, 512, 0, stream>>>(o, Woutb, bout, P1);
  // 4. x2 = rmsnorm(a + ALPHA*x, g1)
  rmsnorm_mid<<<4096, 256, 0, stream>>>(P1, x, g1, x2);
  // 5. W1 GEMM + fused SwiGLU -> ys  (depth-2 split-lgkm 4-phase)
  gemm_w1_swiglu_s4<<<512, 512, 0, stream>>>(x2, W1b, ys);
  // 6. y2 = ys @ W2^T (split-K=2, 2-phase) -> p0,p1 f32  (REVERTED)
  gemm_w2_2ph<<<256, 512, 0, stream>>>(ys, W2b, p0);
  // 7. out = rmsnorm(p0+p1 + ALPHA*x2, g2)
  rmsnorm_final_sk<<<4096, 256, 0, stream>>>(p0, p0 + 4194304, x2, g2, out);
}